// Round 10
// baseline (80.297 us; speedup 1.0000x reference)
//
#include <hip/hip_runtime.h>
#include <stdint.h>

#define BB 8
#define NN 2048
#define IND 10
#define QK 32

// Kernel 1: q[b][n][qd] = sum_d s[b,n,d]*Wq[qd,d]; k likewise.
// kt permuted for kernel 2's read: attn thread (wave w, lane i) owns cols
//   {512w + 4i + j : j=0..3} and {512w + 256 + 4i + j : j=0..3}.
// kt float4 index: (b*4+w)*4096 + (ev*8+jc)*64 + i, component c (qd=4ev+c).
__global__ __launch_bounds__(256) void qk_kernel(
    const float* __restrict__ s,
    const float* __restrict__ Wq, const float* __restrict__ Wk,
    float* __restrict__ q_ws, float* __restrict__ kt_ws) {
  int t = blockIdx.x * 256 + threadIdx.x;      // 0 .. B*N*QK-1 (exact)
  int b  = t >> 16;                            // N*QK = 65536
  int n  = (t >> 5) & (NN - 1);
  int qd = t & 31;
  const float* srow = s + (size_t)(b * NN + n) * IND;
  float acq = 0.f, ack = 0.f;
#pragma unroll
  for (int d = 0; d < IND; ++d) {
    float sv = srow[d];
    acq = fmaf(sv, Wq[qd * IND + d], acq);
    ack = fmaf(sv, Wk[qd * IND + d], ack);
  }
  q_ws[(size_t)(b * NN + n) * QK + qd] = acq;
  int w  = n >> 9;                 // wave (512 cols each)
  int m  = n & 511;
  int i  = (m & 255) >> 2;         // lane
  int jc = ((m < 256) ? 0 : 4) + (m & 3);
  int ev = qd >> 2, c = qd & 3;
  kt_ws[(((size_t)(b * 4 + w) * 4096) + (ev * 8 + jc) * 64 + i) * 4 + c] = ack;
}

// Kernel 2: one block = (batch, 4 rows), 256 threads. Thread (w,lane) owns
// cols {512w+4*lane+j} and {512w+256+4*lane+j}, j=0..3, for all 4 rows.
// R9 structure (no pinning, no fences, stream-G epilogue) with ROWS=4:
// acc[4][8]=32 regs -> VGPR ~64-80 -> 6-8 waves/SIMD theoretical, double
// R9's co-residency. Latency hiding via TLP, not intra-wave scheduling.
__global__ __launch_bounds__(256) void attn_kernel(
    const float* __restrict__ G,
    const float* __restrict__ q_ws, const float* __restrict__ kt_ws,
    float* __restrict__ out) {
  const int tid = threadIdx.x;
  const int b = blockIdx.y;
  const int r0 = blockIdx.x * 4;
  const int w = tid >> 6, lane = tid & 63;

  __shared__ float q_lds[4][128];  // wave-private q tile copies (512 B/wave)
  __shared__ float red[4][4];

  // ---- wave-private q copy (4 rows x 32 = 128 contiguous floats) ----
  {
    const float* qb = q_ws + ((size_t)b * NN + r0) * QK;
    *(float2*)&q_lds[w][2 * lane] = *(const float2*)&qb[2 * lane];
  }

  // ---- GEMM: acc[r][j] = q[r0+r] . k[col(w,lane,j)] ----
  float acc[4][8];
#pragma unroll
  for (int r = 0; r < 4; ++r)
#pragma unroll
    for (int j = 0; j < 8; ++j) acc[r][j] = 0.f;

  const float4* kt =
      (const float4*)kt_ws + (size_t)(b * 4 + w) * 4096 + lane;

#pragma unroll
  for (int ev = 0; ev < 8; ++ev) {
    float q4[4][4];
#pragma unroll
    for (int r = 0; r < 4; ++r)
      *(float4*)q4[r] = *(const float4*)&q_lds[w][r * 32 + ev * 4];
#pragma unroll
    for (int j = 0; j < 8; ++j) {
      float4 k4 = kt[(ev * 8 + j) * 64];  // lane-coalesced, L2-resident
#pragma unroll
      for (int r = 0; r < 4; ++r) {
        acc[r][j] = fmaf(q4[r][0], k4.x, acc[r][j]);
        acc[r][j] = fmaf(q4[r][1], k4.y, acc[r][j]);
        acc[r][j] = fmaf(q4[r][2], k4.z, acc[r][j]);
        acc[r][j] = fmaf(q4[r][3], k4.w, acc[r][j]);
      }
    }
  }

  // ---- stream G row-by-row: v = logits^2 * G, row partials, butterfly ----
  const float* gb = G + ((size_t)b * NN + r0) * NN + 512 * w + 4 * lane;
  float rsum[4];
#pragma unroll
  for (int r = 0; r < 4; ++r) {
    float gg[8];
    *(float4*)&gg[0] = *(const float4*)(gb + (size_t)r * NN);
    *(float4*)&gg[4] = *(const float4*)(gb + (size_t)r * NN + 256);
    float sum = 0.f;
#pragma unroll
    for (int j = 0; j < 8; ++j) {
      float v = acc[r][j];
      v = v * v * gg[j];
      acc[r][j] = v;
      sum += v;
    }
#pragma unroll
    for (int off = 32; off >= 1; off >>= 1) sum += __shfl_xor(sum, off, 64);
    rsum[r] = sum;
  }

  // ---- cross-wave reduce ----
  if ((tid & 63) == 0) {
#pragma unroll
    for (int r = 0; r < 4; ++r) red[w][r] = rsum[r];
  }
  __syncthreads();

  float inv[4];
#pragma unroll
  for (int r = 0; r < 4; ++r) {
    float total = red[0][r] + red[1][r] + red[2][r] + red[3][r];
    inv[r] = 1.0f / (total + 1e-6f);
  }

  // ---- scale + coalesced store ----
  float* ob = out + ((size_t)b * NN + r0) * NN + 512 * w + 4 * lane;
#pragma unroll
  for (int r = 0; r < 4; ++r) {
    float4 o0, o1;
    o0.x = acc[r][0] * inv[r]; o0.y = acc[r][1] * inv[r];
    o0.z = acc[r][2] * inv[r]; o0.w = acc[r][3] * inv[r];
    o1.x = acc[r][4] * inv[r]; o1.y = acc[r][5] * inv[r];
    o1.z = acc[r][6] * inv[r]; o1.w = acc[r][7] * inv[r];
    *(float4*)(ob + (size_t)r * NN)       = o0;
    *(float4*)(ob + (size_t)r * NN + 256) = o1;
  }
}

extern "C" void kernel_launch(void* const* d_in, const int* in_sizes, int n_in,
                              void* d_out, int out_size, void* d_ws, size_t ws_size,
                              hipStream_t stream) {
  const float* s  = (const float*)d_in[0];
  const float* G  = (const float*)d_in[1];
  const float* Wq = (const float*)d_in[2];
  const float* Wk = (const float*)d_in[3];
  float* out = (float*)d_out;

  float* q_ws  = (float*)d_ws;                       // B*N*QK floats = 2 MB
  float* kt_ws = q_ws + (size_t)BB * NN * QK;        // another 2 MB

  qk_kernel<<<(BB * NN * QK) / 256, 256, 0, stream>>>(s, Wq, Wk, q_ws, kt_ws);

  dim3 grid(NN / 4, BB);
  attn_kernel<<<grid, 256, 0, stream>>>(G, q_ws, kt_ws, out);
}

// Round 11
// 77.263 us; speedup vs baseline: 1.0393x; 1.0393x over previous
//
#include <hip/hip_runtime.h>
#include <stdint.h>

#define BB 8
#define NN 2048
#define IND 10
#define QK 32

// Kernel 1: q[b][n][qd] = sum_d s[b,n,d]*Wq[qd,d]; k likewise.
// kt permuted for kernel 2's 16x256 wave tile: attn thread (wave w in [0,8),
// lane i) owns cols {256w + 4i + j : j=0..3}. Per ev it loads 4 float4s,
// j-th at float4-index ((b*8+w)*8 + ev)*256 + j*64 + i  -> consecutive
// lanes hit consecutive float4s (perfect 1KB/instr coalescing).
__global__ __launch_bounds__(256) void qk_kernel(
    const float* __restrict__ s,
    const float* __restrict__ Wq, const float* __restrict__ Wk,
    float* __restrict__ q_ws, float* __restrict__ kt_ws) {
  int t = blockIdx.x * 256 + threadIdx.x;      // 0 .. B*N*QK-1 (exact)
  int b  = t >> 16;                            // N*QK = 65536
  int n  = (t >> 5) & (NN - 1);
  int qd = t & 31;
  const float* srow = s + (size_t)(b * NN + n) * IND;
  float acq = 0.f, ack = 0.f;
#pragma unroll
  for (int d = 0; d < IND; ++d) {
    float sv = srow[d];
    acq = fmaf(sv, Wq[qd * IND + d], acq);
    ack = fmaf(sv, Wk[qd * IND + d], ack);
  }
  q_ws[(size_t)(b * NN + n) * QK + qd] = acq;
  int w  = n >> 8;          // wave (256 cols each)
  int i  = (n >> 2) & 63;   // lane
  int j  = n & 3;           // col within thread's 4
  int ev = qd >> 2, c = qd & 3;
  kt_ws[((((size_t)(b * 8 + w) * 8) + ev) * 256 + j * 64 + i) * 4 + c] = ack;
}

// Kernel 2: one block = (batch, 16 rows), 512 threads (8 waves). Wave w owns
// cols [256w, 256w+256); thread (w,lane) owns cols 256w+4*lane..+3 for all
// 16 rows. Same acc count (64), FMA count, and G/store instruction count as
// R9's 8x512 tile, but HALF the k loads (32 vs 64) and half the total k L2
// traffic (268 MB). No pinning, no fences, no launch-bounds cap: latency is
// handled by the compiler's own scheduling + TLP.
__global__ __launch_bounds__(512) void attn_kernel(
    const float* __restrict__ G,
    const float* __restrict__ q_ws, const float* __restrict__ kt_ws,
    float* __restrict__ out) {
  const int tid = threadIdx.x;
  const int b = blockIdx.y;
  const int r0 = blockIdx.x * 16;
  const int w = tid >> 6, lane = tid & 63;

  __shared__ float q_lds[16 * 32];  // block-shared q tile (2 KB)
  __shared__ float red[8][16];

  // ---- q stage: 16 rows x 32 = 512 contiguous floats, one per thread ----
  q_lds[tid] = q_ws[((size_t)b * NN + r0) * QK + tid];
  __syncthreads();

  // ---- GEMM: acc[r][j] = q[r0+r] . k[col = 256w + 4*lane + j] ----
  float acc[16][4];
#pragma unroll
  for (int r = 0; r < 16; ++r)
#pragma unroll
    for (int j = 0; j < 4; ++j) acc[r][j] = 0.f;

  const float4* kt =
      (const float4*)kt_ws + ((size_t)(b * 8 + w) * 8) * 256 + lane;

#pragma unroll
  for (int ev = 0; ev < 8; ++ev) {
    float4 k4[4];
#pragma unroll
    for (int j = 0; j < 4; ++j) k4[j] = kt[ev * 256 + j * 64];  // coalesced
#pragma unroll
    for (int r = 0; r < 16; ++r) {
      float q4[4];
      *(float4*)q4 = *(const float4*)&q_lds[r * 32 + ev * 4];  // broadcast
#pragma unroll
      for (int j = 0; j < 4; ++j) {
        acc[r][j] = fmaf(q4[0], k4[j].x, acc[r][j]);
        acc[r][j] = fmaf(q4[1], k4[j].y, acc[r][j]);
        acc[r][j] = fmaf(q4[2], k4[j].z, acc[r][j]);
        acc[r][j] = fmaf(q4[3], k4[j].w, acc[r][j]);
      }
    }
  }

  // ---- stream G row-by-row: v = logits^2 * G, row partials, butterfly ----
  const float* gb = G + ((size_t)b * NN + r0) * NN + 256 * w + 4 * lane;
  float rsum[16];
#pragma unroll
  for (int r = 0; r < 16; ++r) {
    float gg[4];
    *(float4*)gg = *(const float4*)(gb + (size_t)r * NN);
    float sum = 0.f;
#pragma unroll
    for (int j = 0; j < 4; ++j) {
      float v = acc[r][j];
      v = v * v * gg[j];
      acc[r][j] = v;
      sum += v;
    }
#pragma unroll
    for (int off = 32; off >= 1; off >>= 1) sum += __shfl_xor(sum, off, 64);
    rsum[r] = sum;
  }

  // ---- cross-wave reduce (8 waves) ----
  if ((tid & 63) == 0) {
#pragma unroll
    for (int r = 0; r < 16; ++r) red[w][r] = rsum[r];
  }
  __syncthreads();

  float inv[16];
#pragma unroll
  for (int r = 0; r < 16; ++r) {
    float total = 0.f;
#pragma unroll
    for (int w2 = 0; w2 < 8; ++w2) total += red[w2][r];  // uniform broadcast
    inv[r] = 1.0f / (total + 1e-6f);
  }

  // ---- scale + coalesced store ----
  float* ob = out + ((size_t)b * NN + r0) * NN + 256 * w + 4 * lane;
#pragma unroll
  for (int r = 0; r < 16; ++r) {
    float4 o;
    o.x = acc[r][0] * inv[r];
    o.y = acc[r][1] * inv[r];
    o.z = acc[r][2] * inv[r];
    o.w = acc[r][3] * inv[r];
    *(float4*)(ob + (size_t)r * NN) = o;
  }
}

extern "C" void kernel_launch(void* const* d_in, const int* in_sizes, int n_in,
                              void* d_out, int out_size, void* d_ws, size_t ws_size,
                              hipStream_t stream) {
  const float* s  = (const float*)d_in[0];
  const float* G  = (const float*)d_in[1];
  const float* Wq = (const float*)d_in[2];
  const float* Wk = (const float*)d_in[3];
  float* out = (float*)d_out;

  float* q_ws  = (float*)d_ws;                       // B*N*QK floats = 2 MB
  float* kt_ws = q_ws + (size_t)BB * NN * QK;        // another 2 MB

  qk_kernel<<<(BB * NN * QK) / 256, 256, 0, stream>>>(s, Wq, Wk, q_ws, kt_ws);

  dim3 grid(NN / 16, BB);
  attn_kernel<<<grid, 512, 0, stream>>>(G, q_ws, kt_ws, out);
}